// Round 4
// baseline (360.736 us; speedup 1.0000x reference)
//
#include <hip/hip_runtime.h>
#include <stdint.h>

typedef __attribute__((ext_vector_type(8))) _Float16 half8;  // MFMA f16 A/B frag (4 VGPRs)
typedef __attribute__((ext_vector_type(4))) float f32x4;     // MFMA C/D frag

// B=4, C=384, Q=384, H=256, K=256.  w1 is (256 k-rows, 768 h-cols):
//   W_h[k][h]=w1[k][h], W_u[k][h]=w1[k][256+h], W_hu[k][h]=w1[k][512+h]
// Identity used:  pre1[q,k] = sum_h (u*h)·W_hu  +  (sum_h u·W_u)  +  (th[c,k]+b1[k])
//                              ^ per-c MFMA        ^ tuacc (once/block, registers)

__device__ __forceinline__ float leaky(float x) { return fmaxf(x, 0.01f * x); }

template <int CTRL>
__device__ __forceinline__ float dpp_add(float x) {
  int t = __builtin_amdgcn_update_dpp(0, __float_as_int(x), CTRL, 0xF, 0xF, true);
  return x + __int_as_float(t);
}
// 16-lane sum within each aligned 16-lane row
__device__ __forceinline__ float row16_sum(float p) {
  p = dpp_add<0xB1>(p);   // quad_perm(1,0,3,2) = xor 1
  p = dpp_add<0x4E>(p);   // quad_perm(2,3,0,1) = xor 2
  p = dpp_add<0x124>(p);  // row_ror:4
  p = dpp_add<0x128>(p);  // row_ror:8
  return p;
}

__device__ __forceinline__ half8 cvt8(const float* p) {
  float4 a0 = *(const float4*)p;
  float4 a1 = *(const float4*)(p + 4);
  half8 h;
  h[0] = (_Float16)a0.x; h[1] = (_Float16)a0.y;
  h[2] = (_Float16)a0.z; h[3] = (_Float16)a0.w;
  h[4] = (_Float16)a1.x; h[5] = (_Float16)a1.y;
  h[6] = (_Float16)a1.z; h[7] = (_Float16)a1.w;
  return h;
}

// Single fused kernel. Block = (b, 24 c-rows, 16 q-rows); 256 thr = 4 waves,
// wave w owns k in [w*64, w*64+64), lane (quad,r) holds k = w*64 + 4r + j.
// Register budget/lane: whu 128 + ufr 32 + tuacc 16 + acc 16 + temps ~= 225 < 256
// -> __launch_bounds__(256,2): 2 blocks/CU, LDS 37.3KB*2 fits 160KB.
__global__ void __launch_bounds__(256, 2) k_main(
    const float* __restrict__ hp, const float* __restrict__ up,
    const float* __restrict__ w1, const float* __restrict__ b1,
    const float* __restrict__ w2, const float* __restrict__ b2,
    float* __restrict__ out) {
  __shared__ __align__(16) float thlds[24 * 256];      // th + b1, fp32, 24 KB
  __shared__ __align__(16) _Float16 hlds[24 * 264];    // h rows fp16, stride 264 (bank-pad)
  __shared__ float redw[2][4][16];

  const int tid = threadIdx.x;
  const int blk = blockIdx.x;            // 1536 = 4b * 16cc * 24qt
  const int b = blk / 384;
  const int rem = blk % 384;
  const int cc = rem / 24;
  const int qt = rem % 24;
  const int q0 = qt * 16;
  const int c0 = cc * 24;

  const int w = tid >> 6, l = tid & 63, quad = l >> 4, r = l & 15;
  const int kbase = w * 64 + r * 4;      // lane's 4 k-columns = kbase + j

  // ---- stage h rows -> LDS fp16 (stride 264 halfs = 528 B) ----
  for (int idx = tid; idx < 24 * 64; idx += 256) {
    int c = idx >> 6;
    int hh = (idx & 63) * 4;
    float4 v = *(const float4*)(hp + (b * 384 + c0 + c) * 256 + hh);
    unsigned int lo = (unsigned int)__builtin_bit_cast(unsigned short, (_Float16)v.x) |
                      ((unsigned int)__builtin_bit_cast(unsigned short, (_Float16)v.y) << 16);
    unsigned int hi = (unsigned int)__builtin_bit_cast(unsigned short, (_Float16)v.z) |
                      ((unsigned int)__builtin_bit_cast(unsigned short, (_Float16)v.w) << 16);
    *(uint2*)((char*)hlds + c * 528 + hh * 2) = make_uint2(lo, hi);
  }

  // ---- one-time register frags: u (A operand) and W_hu (B operand) ----
  half8 ufr[8];                          // u[q0+r][s*32+quad*8 .. +8]
#pragma unroll
  for (int s = 0; s < 8; ++s)
    ufr[s] = cvt8(up + (b * 384 + q0 + r) * 256 + s * 32 + quad * 8);
  half8 whu[4][8];
#pragma unroll
  for (int j = 0; j < 4; ++j) {
    const float* rw = w1 + (kbase + j) * 768 + 512 + quad * 8;   // W_hu row
#pragma unroll
    for (int s = 0; s < 8; ++s) whu[j][s] = cvt8(rw + s * 32);
  }

  // ---- tu prologue: tuacc[j] = sum_h u[q,h]*W_u[k,h]  (D-layout, stays in regs) ----
  f32x4 tuacc[4];
#pragma unroll
  for (int j = 0; j < 4; ++j) tuacc[j] = (f32x4){0.f, 0.f, 0.f, 0.f};
#pragma unroll
  for (int s = 0; s < 8; ++s)
#pragma unroll
    for (int j = 0; j < 4; ++j) {
      half8 wb = cvt8(w1 + (kbase + j) * 768 + 256 + s * 32 + quad * 8);  // W_u row
      tuacc[j] = __builtin_amdgcn_mfma_f32_16x16x32_f16(ufr[s], wb, tuacc[j], 0, 0, 0);
    }

  __syncthreads();   // hlds ready

  // ---- th prologue: (th + b1) for the block's 24 c-rows -> thlds ----
  f32x4 b1v = *(const f32x4*)(b1 + kbase);
#pragma unroll
  for (int ct = 0; ct < 2; ++ct) {
    f32x4 accq[4];
#pragma unroll
    for (int j = 0; j < 4; ++j) accq[j] = (f32x4){0.f, 0.f, 0.f, 0.f};
#pragma unroll
    for (int s = 0; s < 8; ++s) {
      half8 ha = (half8){};
      if (ct * 16 + r < 24)
        ha = *(const half8*)((const char*)hlds + (ct * 16 + r) * 528 + (s * 32 + quad * 8) * 2);
#pragma unroll
      for (int j = 0; j < 4; ++j) {
        half8 wb = cvt8(w1 + (kbase + j) * 768 + s * 32 + quad * 8);      // W_h row
        accq[j] = __builtin_amdgcn_mfma_f32_16x16x32_f16(ha, wb, accq[j], 0, 0, 0);
      }
    }
#pragma unroll
    for (int ii = 0; ii < 4; ++ii) {
      int crow = ct * 16 + quad * 4 + ii;
      if (crow < 24) {
        f32x4 v = {accq[0][ii] + b1v[0], accq[1][ii] + b1v[1],
                   accq[2][ii] + b1v[2], accq[3][ii] + b1v[3]};
        *(f32x4*)&thlds[crow * 256 + kbase] = v;
      }
    }
  }
  __syncthreads();   // thlds ready

  // ---- main c-loop: zero barriers in the MFMA stretch ----
  f32x4 w2v = *(const f32x4*)(w2 + kbase);
  f32x4 w2a = w2v * 0.505f;     // leaky(x)*w2 = w2*(0.505x + 0.495|x|)
  f32x4 w2b = w2v * 0.495f;
  const float b2v = b2[0];
  int par = 0;

  for (int c = 0; c < 24; ++c) {
    f32x4 thv = *(const f32x4*)&thlds[c * 256 + kbase];
    f32x4 acc[4];
#pragma unroll
    for (int j = 0; j < 4; ++j) acc[j] = tuacc[j] + thv[j];

    const char* hrow = (const char*)hlds + c * 528 + quad * 16;
#pragma unroll
    for (int s = 0; s < 8; ++s) {
      half8 hc = *(const half8*)(hrow + s * 64);       // broadcast across r-lanes
      half8 a = ufr[s] * hc;                           // 4x v_pk_mul_f16
#pragma unroll
      for (int j = 0; j < 4; ++j)
        acc[j] = __builtin_amdgcn_mfma_f32_16x16x32_f16(a, whu[j][s], acc[j], 0, 0, 0);
    }

    // layer-2: dot over lane's 4 k, DPP-sum over 16 r-lanes, LDS across 4 waves
#pragma unroll
    for (int ii = 0; ii < 4; ++ii) {
      float p = 0.f;
#pragma unroll
      for (int j = 0; j < 4; ++j) {
        float sv = acc[j][ii];
        p = fmaf(w2a[j], sv, p);
        p = fmaf(w2b[j], fabsf(sv), p);
      }
      p = row16_sum(p);
      if (r == 0) redw[par][w][quad * 4 + ii] = p;
    }
    __syncthreads();
    if (tid < 16) {
      float o = redw[par][0][tid] + redw[par][1][tid] + redw[par][2][tid] +
                redw[par][3][tid] + b2v;
      out[(b * 384 + c0 + c) * 384 + q0 + tid] = leaky(o);
    }
    par ^= 1;
  }
}

extern "C" void kernel_launch(void* const* d_in, const int* in_sizes, int n_in,
                              void* d_out, int out_size, void* d_ws, size_t ws_size,
                              hipStream_t stream) {
  const float* hp = (const float*)d_in[0];   // (4,384,256)
  const float* up = (const float*)d_in[1];   // (4,384,256)
  const float* w1 = (const float*)d_in[2];   // (256,768) — axis-0 is k
  const float* b1 = (const float*)d_in[3];   // (256,)
  const float* w2 = (const float*)d_in[4];   // (1,256)
  const float* b2 = (const float*)d_in[5];   // (1,)
  float* out = (float*)d_out;                // (4,384,384)

  k_main<<<1536, 256, 0, stream>>>(hp, up, w1, b1, w2, b2, out);
}

// Round 5
// 275.407 us; speedup vs baseline: 1.3098x; 1.3098x over previous
//
#include <hip/hip_runtime.h>
#include <stdint.h>

typedef __attribute__((ext_vector_type(8))) _Float16 half8;  // MFMA f16 A/B frag (4 VGPRs)
typedef __attribute__((ext_vector_type(4))) float f32x4;     // MFMA C/D frag

// B=4, C=384, Q=384, H=256, K=256.  w1 is (256 k-rows, 768 h-cols):
//   W_h[k][h]=w1[k][h], W_u[k][h]=w1[k][256+h], W_hu[k][h]=w1[k][512+h]
// pre1[c,q,k] = sum_h (u*h)·W_hu + tu[q,k] + th[c,k] + b1[k]
// out[c,q]    = leaky( sum_k leaky(pre1)·w2[k] + b2 )
// ws: [0, 393216)          fp16 [3][256][256] = W_h, W_u, W_hu  (k_convert)
//     [393216, 2752512)    fp32 partial sums (4*384*384), atomically accumulated

__device__ __forceinline__ float leaky(float x) { return fmaxf(x, 0.01f * x); }

template <int CTRL>
__device__ __forceinline__ float dpp_add(float x) {
  int t = __builtin_amdgcn_update_dpp(0, __float_as_int(x), CTRL, 0xF, 0xF, true);
  return x + __int_as_float(t);
}
// sum across the 16 lanes of an aligned 16-lane row (r = lane&15)
__device__ __forceinline__ float row16_sum(float p) {
  p = dpp_add<0xB1>(p);   // quad_perm xor1
  p = dpp_add<0x4E>(p);   // quad_perm xor2
  p = dpp_add<0x124>(p);  // row_ror:4
  p = dpp_add<0x128>(p);  // row_ror:8
  return p;
}

__device__ __forceinline__ half8 cvt8(const float* p) {
  float4 a0 = *(const float4*)p;
  float4 a1 = *(const float4*)(p + 4);
  half8 h;
  h[0] = (_Float16)a0.x; h[1] = (_Float16)a0.y;
  h[2] = (_Float16)a0.z; h[3] = (_Float16)a0.w;
  h[4] = (_Float16)a1.x; h[5] = (_Float16)a1.y;
  h[6] = (_Float16)a1.z; h[7] = (_Float16)a1.w;
  return h;
}

// ---------------- K0: split w1 -> fp16 [3][k][h]  (verified in R3) ----------------
__global__ void k_convert(const float* __restrict__ w1, unsigned int* __restrict__ ws) {
  int d = blockIdx.x * 256 + threadIdx.x;        // 98304 dwords
  int m = d >> 15;
  int rem = d & 32767;
  int k = rem >> 7;
  int h2 = (rem & 127) * 2;
  float x0 = w1[k * 768 + m * 256 + h2];
  float x1 = w1[k * 768 + m * 256 + h2 + 1];
  unsigned short p0 = __builtin_bit_cast(unsigned short, (_Float16)x0);
  unsigned short p1 = __builtin_bit_cast(unsigned short, (_Float16)x1);
  ws[d] = (unsigned int)p0 | ((unsigned int)p1 << 16);
}

// ---------------- K1: main. Block = 128 q x 64 k (kt-split) x 12 c ------------------
// 4 waves split q (wq = w). Lane (quad,r): k = kt*64 + 4r + j, j=0..3.
// Register tile: ufr[2] (resident) x j=4 (LDS) x c-batch 2 -> 0.375 LDS reads/MFMA.
// No barriers in the main loop; k-split combined via atomicAdd into `part`.
__global__ void __launch_bounds__(256, 2) k_main(
    const float* __restrict__ hp, const float* __restrict__ up,
    const _Float16* __restrict__ ws16,
    const float* __restrict__ b1, const float* __restrict__ w2,
    float* __restrict__ part) {
  __shared__ __align__(16) _Float16 whuL[64 * 256];   // 32 KB, XOR-swizzled slots
  __shared__ __align__(16) _Float16 hlds[12 * 256];   // 6 KB
  __shared__ __align__(16) float thlds[12 * 64];      // 3 KB (th + b1, this k-slice)

  const int tid = threadIdx.x;
  int t = blockIdx.x;                  // 1536 = kt(4) + 4*(qt(3) + 3*(cc(32) + 32*b(4)))
  const int kt = t & 3;  t >>= 2;
  const int qt = t % 3;  t /= 3;
  const int cc = t & 31;
  const int b = t >> 5;
  const int c0 = cc * 12;

  const int w = tid >> 6, l = tid & 63, quad = l >> 4, r = l & 15;
  const int kbase = kt * 64 + r * 4;   // lane's 4 k = kbase + j

  const _Float16* Wh = ws16;
  const _Float16* Wu = ws16 + 65536;
  const _Float16* Whu = ws16 + 131072;

  // ---- stage W_hu k-slice -> LDS, swizzled: element (krel,h) at slot (h>>3)^((krel>>2)&7)
#pragma unroll
  for (int it = 0; it < 8; ++it) {
    int chunk = tid + it * 256;        // 2048 chunks of 8 halfs
    int krel = chunk >> 5;
    int slot = chunk & 31;
    int hsrc = (slot ^ ((krel >> 2) & 7)) * 8;
    half8 v = *(const half8*)(Whu + (kt * 64 + krel) * 256 + hsrc);
    *(half8*)&whuL[krel * 256 + slot * 8] = v;
  }
  // ---- stage h rows -> LDS fp16 ----
#pragma unroll
  for (int it = 0; it < 3; ++it) {
    int idx = tid + it * 256;          // 768 chunks of 4 halfs
    int c = idx >> 6;
    int hh = (idx & 63) * 4;
    float4 v = *(const float4*)(hp + (b * 384 + c0 + c) * 256 + hh);
    unsigned int lo = (unsigned int)__builtin_bit_cast(unsigned short, (_Float16)v.x) |
                      ((unsigned int)__builtin_bit_cast(unsigned short, (_Float16)v.y) << 16);
    unsigned int hi = (unsigned int)__builtin_bit_cast(unsigned short, (_Float16)v.z) |
                      ((unsigned int)__builtin_bit_cast(unsigned short, (_Float16)v.w) << 16);
    *(uint2*)&hlds[c * 256 + hh] = make_uint2(lo, hi);
  }

  // ---- resident u frags: q = qt*128 + wq*32 + i*16 + r ----
  half8 ufr[2][8];
#pragma unroll
  for (int i = 0; i < 2; ++i) {
    const float* urow = up + (b * 384 + qt * 128 + w * 32 + i * 16 + r) * 256 + quad * 8;
#pragma unroll
    for (int s = 0; s < 8; ++s) ufr[i][s] = cvt8(urow + s * 32);
  }

  // ---- tu prologue (registers; B-frags of W_u straight from L2) ----
  f32x4 tuacc[2][4];
#pragma unroll
  for (int i = 0; i < 2; ++i)
#pragma unroll
    for (int j = 0; j < 4; ++j) tuacc[i][j] = (f32x4){0.f, 0.f, 0.f, 0.f};
#pragma unroll
  for (int s = 0; s < 8; ++s)
#pragma unroll
    for (int j = 0; j < 4; ++j) {
      half8 wb = *(const half8*)(Wu + (kbase + j) * 256 + s * 32 + quad * 8);
#pragma unroll
      for (int i = 0; i < 2; ++i)
        tuacc[i][j] = __builtin_amdgcn_mfma_f32_16x16x32_f16(ufr[i][s], wb, tuacc[i][j], 0, 0, 0);
    }

  __syncthreads();   // whuL + hlds ready

  // ---- th prologue: (th + b1) for 12 c-rows x this 64-k slice -> thlds ----
  {
    f32x4 accq[4];
#pragma unroll
    for (int j = 0; j < 4; ++j) accq[j] = (f32x4){0.f, 0.f, 0.f, 0.f};
#pragma unroll
    for (int s = 0; s < 8; ++s) {
      half8 ha = (half8){};
      if (r < 12) ha = *(const half8*)&hlds[r * 256 + s * 32 + quad * 8];
#pragma unroll
      for (int j = 0; j < 4; ++j) {
        half8 wb = *(const half8*)(Wh + (kbase + j) * 256 + s * 32 + quad * 8);
        accq[j] = __builtin_amdgcn_mfma_f32_16x16x32_f16(ha, wb, accq[j], 0, 0, 0);
      }
    }
    f32x4 b1v = *(const f32x4*)(b1 + kbase);
#pragma unroll
    for (int ii = 0; ii < 4; ++ii) {
      int crow = quad * 4 + ii;
      if (crow < 12) {
        f32x4 v = {accq[0][ii] + b1v[0], accq[1][ii] + b1v[1],
                   accq[2][ii] + b1v[2], accq[3][ii] + b1v[3]};
        *(f32x4*)&thlds[crow * 64 + r * 4] = v;
      }
    }
  }
  __syncthreads();   // thlds ready — no more barriers

  f32x4 w2v = *(const f32x4*)(w2 + kbase);
  f32x4 w2a = w2v * 0.505f;     // leaky(x)*w2 = w2*(0.505x + 0.495|x|)
  f32x4 w2b = w2v * 0.495f;
  const int rs = r & 7;         // reader-side slot swizzle

  for (int cp = 0; cp < 6; ++cp) {
    f32x4 th0 = *(const f32x4*)&thlds[(2 * cp) * 64 + r * 4];
    f32x4 th1 = *(const f32x4*)&thlds[(2 * cp + 1) * 64 + r * 4];
    f32x4 acc[2][2][4];
#pragma unroll
    for (int i = 0; i < 2; ++i)
#pragma unroll
      for (int j = 0; j < 4; ++j) {
        acc[0][i][j] = tuacc[i][j] + th0[j];
        acc[1][i][j] = tuacc[i][j] + th1[j];
      }

#pragma unroll
    for (int s = 0; s < 8; ++s) {
      half8 hc0 = *(const half8*)&hlds[(2 * cp) * 256 + s * 32 + quad * 8];
      half8 hc1 = *(const half8*)&hlds[(2 * cp + 1) * 256 + s * 32 + quad * 8];
      half8 bf[4];
#pragma unroll
      for (int j = 0; j < 4; ++j) {
        int krel = r * 4 + j;
        int slot = (s * 4 + quad) ^ rs;
        bf[j] = *(const half8*)&whuL[krel * 256 + slot * 8];
      }
      half8 a[2][2];
#pragma unroll
      for (int i = 0; i < 2; ++i) { a[0][i] = ufr[i][s] * hc0; a[1][i] = ufr[i][s] * hc1; }
#pragma unroll
      for (int c2 = 0; c2 < 2; ++c2)
#pragma unroll
        for (int i = 0; i < 2; ++i)
#pragma unroll
          for (int j = 0; j < 4; ++j)
            acc[c2][i][j] =
                __builtin_amdgcn_mfma_f32_16x16x32_f16(a[c2][i], bf[j], acc[c2][i][j], 0, 0, 0);
    }

    // epilogue: layer-2 partial over this wave's 64 k -> atomicAdd into part
#pragma unroll
    for (int c2 = 0; c2 < 2; ++c2) {
      int cg = (b * 384 + c0 + 2 * cp + c2) * 384 + qt * 128 + w * 32;
#pragma unroll
      for (int i = 0; i < 2; ++i)
#pragma unroll
        for (int ii = 0; ii < 4; ++ii) {
          float p = 0.f;
#pragma unroll
          for (int j = 0; j < 4; ++j) {
            float sv = acc[c2][i][j][ii];
            p = fmaf(w2a[j], sv, p);
            p = fmaf(w2b[j], fabsf(sv), p);
          }
          p = row16_sum(p);
          if (r == 0) atomicAdd(&part[cg + i * 16 + quad * 4 + ii], p);
        }
    }
  }
}

// ---------------- K2: out = leaky(partial + b2) -------------------------------------
__global__ void k_final(const float* __restrict__ part, const float* __restrict__ b2,
                        float* __restrict__ out) {
  int i = blockIdx.x * 256 + threadIdx.x;        // 589824 exact
  out[i] = leaky(part[i] + b2[0]);
}

extern "C" void kernel_launch(void* const* d_in, const int* in_sizes, int n_in,
                              void* d_out, int out_size, void* d_ws, size_t ws_size,
                              hipStream_t stream) {
  const float* hp = (const float*)d_in[0];   // (4,384,256)
  const float* up = (const float*)d_in[1];   // (4,384,256)
  const float* w1 = (const float*)d_in[2];   // (256,768) — axis-0 is k
  const float* b1 = (const float*)d_in[3];   // (256,)
  const float* w2 = (const float*)d_in[4];   // (1,256)
  const float* b2 = (const float*)d_in[5];   // (1,)
  float* out = (float*)d_out;                // (4,384,384)

  float* part = (float*)((char*)d_ws + 393216);

  hipMemsetAsync(part, 0, 4 * 384 * 384 * sizeof(float), stream);
  k_convert<<<384, 256, 0, stream>>>(w1, (unsigned int*)d_ws);
  k_main<<<1536, 256, 0, stream>>>(hp, up, (const _Float16*)d_ws, b1, w2, part);
  k_final<<<2304, 256, 0, stream>>>(part, b2, out);
}